// Round 12
// baseline (67890.863 us; speedup 1.0000x reference)
//
#include <hip/hip_runtime.h>
#include <hip/hip_bf16.h>

typedef __attribute__((ext_vector_type(8))) _Float16 half8_t;
typedef __attribute__((ext_vector_type(4))) float f32x4_t;
typedef unsigned long long u64;

#define SH 2056                       // LDS h row stride (elems): 2048 + 8
#define HMOFF (16 * SH)               // plane-2 offset (elems)
#define LDS_BYTES (2 * 16 * SH * 2)   // 131,584 B -> 1 WG/CU, 8 waves = 2/SIMD

__device__ __forceinline__ float sigm(float z) { return 1.0f / (1.0f + __expf(-z)); }
__device__ __forceinline__ float tanh_fast(float z) {
  float e = __expf(2.0f * z);
  return 1.0f - 2.0f / (e + 1.0f);
}

// ---- coherent (cross-XCD) access helpers
__device__ __forceinline__ half8_t ld_h8_coh(const _Float16* p) {
  union { half8_t h; u64 q[2]; } r;
  u64* q = (u64*)p;
  r.q[0] = __hip_atomic_load(q,     __ATOMIC_RELAXED, __HIP_MEMORY_SCOPE_SYSTEM);
  r.q[1] = __hip_atomic_load(q + 1, __ATOMIC_RELAXED, __HIP_MEMORY_SCOPE_SYSTEM);
  return r.h;
}
__device__ __forceinline__ void st_h_coh(_Float16* p, _Float16 v) {
  unsigned short b = __builtin_bit_cast(unsigned short, v);
  __hip_atomic_store((unsigned short*)p, b, __ATOMIC_RELAXED, __HIP_MEMORY_SCOPE_SYSTEM);
}
__device__ __forceinline__ float ld_f_coh(const float* p) {
  return __hip_atomic_load((float*)p, __ATOMIC_RELAXED, __HIP_MEMORY_SCOPE_SYSTEM);
}
__device__ __forceinline__ void st_f_coh(float* p, float v) {
  __hip_atomic_store(p, v, __ATOMIC_RELAXED, __HIP_MEMORY_SCOPE_SYSTEM);
}

// ws layout (bytes) — total 59,940,864 (identical to r10/r11, known-good):
//   W0a  @ 0         : 12582912   (fp16 plane1 = fp16(32*w), [gp][k])
//   W0b  @ 12582912  : 12582912
//   W1a  @ 25165824  : 16777216
//   W1b  @ 41943040  : 16777216
//   vecs @ 58720256  : 98304
//   hch  @ 58818560  : 524288     (h plane1 fp16, [row][h0|h1])
//   hcm  @ 59342848  : 524288     (h plane2 fp16, residual*2048)
//   stats@ 59867136  : 65536      (16 reps x 4 bufs x 256 f32)
//   bars @ 59932672  : 8192

// permutation (128-col WG groups): gp = colgrp*128 + w*16 + c,
//   gate = c>>2, uo = c&3 ; gcol = gate*1024 + colgrp*32 + w*4 + uo
__global__ void lstm_prep(const float* __restrict__ W0, const float* __restrict__ W1,
                          const float* __restrict__ b0, const float* __restrict__ g0,
                          const float* __restrict__ be0, const float* __restrict__ b1,
                          const float* __restrict__ g1, const float* __restrict__ be1,
                          _Float16* __restrict__ W0a, _Float16* __restrict__ W0b,
                          _Float16* __restrict__ W1a, _Float16* __restrict__ W1b,
                          float* __restrict__ vecs)
{
  int gid = blockIdx.x * 256 + threadIdx.x;
  const int W0N = 192 * 4096;
  const int W1N = 256 * 4096;
  if (gid < W0N) {
    int k8 = gid >> 12, gp = gid & 4095;
    int colgrp = gp >> 7, w = (gp >> 4) & 7, c = gp & 15;
    int gcol = ((c >> 2) << 10) + (colgrp << 5) + (w << 2) + (c & 3);
    half8_t va, vb;
    #pragma unroll
    for (int j = 0; j < 8; ++j) {
      float w32 = W0[(size_t)(k8 * 8 + j) * 4096 + gcol] * 32.0f;
      _Float16 p1 = (_Float16)w32;
      float r = w32 - (float)p1;
      va[j] = p1; vb[j] = (_Float16)(r * 2048.0f);
    }
    *(half8_t*)&W0a[(size_t)gp * 1536 + k8 * 8] = va;
    *(half8_t*)&W0b[(size_t)gp * 1536 + k8 * 8] = vb;
  } else if (gid < W0N + W1N) {
    int g2 = gid - W0N;
    int k8 = g2 >> 12, gp = g2 & 4095;
    int colgrp = gp >> 7, w = (gp >> 4) & 7, c = gp & 15;
    int gcol = ((c >> 2) << 10) + (colgrp << 5) + (w << 2) + (c & 3);
    half8_t va, vb;
    #pragma unroll
    for (int j = 0; j < 8; ++j) {
      float w32 = W1[(size_t)(k8 * 8 + j) * 4096 + gcol] * 32.0f;
      _Float16 p1 = (_Float16)w32;
      float r = w32 - (float)p1;
      va[j] = p1; vb[j] = (_Float16)(r * 2048.0f);
    }
    *(half8_t*)&W1a[(size_t)gp * 2048 + k8 * 8] = va;
    *(half8_t*)&W1b[(size_t)gp * 2048 + k8 * 8] = vb;
  } else if (gid < W0N + W1N + 6 * 4096) {
    int g2 = gid - W0N - W1N;
    int j = g2 >> 12, gp = g2 & 4095;
    int colgrp = gp >> 7, w = (gp >> 4) & 7, c = gp & 15;
    int gcol = ((c >> 2) << 10) + (colgrp << 5) + (w << 2) + (c & 3);
    const float* src = (j == 0) ? b0 : (j == 1) ? g0 : (j == 2) ? be0
                     : (j == 3) ? b1 : (j == 4) ? g1 : be1;
    vecs[j * 4096 + gp] = src[gcol];
  }
}

#define MFMA16(A, B, C) __builtin_amdgcn_mfma_f32_16x16x32_f16(A, B, C, 0, 0, 0)

// ---- fence-free grid barrier, 256 arrivals (r7-proven 8x32 structure)
__device__ __forceinline__ void gridbar(unsigned* bars, int wgid, int tid, unsigned ep) {
  __syncthreads();
  if (tid == 0) {
    const int q = ep & 1;
    unsigned old = __hip_atomic_fetch_add(&bars[(q * 8 + (wgid & 7)) * 32], 1u,
                                          __ATOMIC_RELAXED, __HIP_MEMORY_SCOPE_AGENT);
    if (old == 31u) {
      unsigned mo = __hip_atomic_fetch_add(&bars[512 + q * 32], 1u,
                                           __ATOMIC_RELAXED, __HIP_MEMORY_SCOPE_AGENT);
      if (mo == 7u) {
        #pragma unroll
        for (int g = 0; g < 8; ++g)
          __hip_atomic_store(&bars[(q * 8 + g) * 32], 0u, __ATOMIC_RELAXED, __HIP_MEMORY_SCOPE_SYSTEM);
        __hip_atomic_store(&bars[512 + q * 32], 0u, __ATOMIC_RELAXED, __HIP_MEMORY_SCOPE_SYSTEM);
        __hip_atomic_store(&bars[576], ep, __ATOMIC_RELEASE, __HIP_MEMORY_SCOPE_SYSTEM);
      }
    }
    while (__hip_atomic_load(&bars[576], __ATOMIC_RELAXED, __HIP_MEMORY_SCOPE_SYSTEM) < ep) {}
  }
  __syncthreads();
}

// 256 WGs x 512 thr. WG = (mtile = wgid>>5, colgrp = wgid&31); wave wid = 16-col
// tile. h staged in LDS per step. Chunk-batched weight loads (deep MLP, r11)
// + PACING gridbars so the 8 mtile-sharers of each colgrp sweep the weight
// stream in lockstep (L2 reuse; r11's 2.4x thrash fix).
__global__ void __launch_bounds__(512, 2) lstm_seq(
    const float* __restrict__ x,
    const _Float16* __restrict__ W0ap,
    const _Float16* __restrict__ W0bp,
    const _Float16* __restrict__ W1ap,
    const _Float16* __restrict__ W1bp,
    const float* __restrict__ vecs,
    _Float16* __restrict__ hch,
    _Float16* __restrict__ hcm,
    float* __restrict__ stats,
    unsigned* __restrict__ bars,
    const float* __restrict__ fcW,
    const float* __restrict__ fcb,
    float* __restrict__ out)
{
  extern __shared__ _Float16 hS[];    // [2 planes][16 rows][SH]
  const int tid = threadIdx.x;
  const int wgid = blockIdx.x;
  const int mtile = wgid >> 5;         // 0..7
  const int colgrp = wgid & 31;        // 0..31 (128-col group)
  const int wid = tid >> 6;            // 0..7 = 16-col tile
  const int lane = tid & 63;
  const int c16 = lane & 15;
  const int klo = lane >> 4;
  const int rowbase = mtile * 16;

  const int gp = colgrp * 128 + wid * 16 + c16;
  const float b0v  = vecs[gp];
  const float g0v  = vecs[4096 + gp];
  const float be0v = vecs[8192 + gp];
  const float b1v  = vecs[12288 + gp];
  const float g1v  = vecs[16384 + gp];
  const float be1v = vecs[20480 + gp];

  const int arow = rowbase + c16;
  const float* xbase = x + (size_t)arow * 512 * 512; // x[row][t][d]
  const _Float16* w0a = W0ap + (size_t)gp * 1536;
  const _Float16* w0b = W0bp + (size_t)gp * 1536;
  const _Float16* w1a = W1ap + (size_t)gp * 2048;
  const _Float16* w1b = W1bp + (size_t)gp * 2048;
  const int repbase = (wgid & 15) << 2;              // rep*4 for stats writes
  const int cbase = colgrp * 32 + wid * 4;           // h-unit base for this wave

  float c0s[4] = {0,0,0,0};
  float c1s[4] = {0,0,0,0};
  unsigned ep = 0;

// stage this WG's 16 h-rows (both planes) -> LDS; batched: 16 loads then 16 writes
#define STAGE_H() {                                                           \
    half8_t tmp_[16];                                                         \
    _Pragma("unroll")                                                         \
    for (int j = 0; j < 16; ++j) {                                            \
      int linear = tid + 512 * j;                                             \
      int plane = linear >> 12;                                               \
      int rem = linear & 4095;                                                \
      int row = rem >> 8;                                                     \
      int ck  = rem & 255;                                                    \
      const _Float16* srcp = (plane ? hcm : hch)                              \
                           + (size_t)(rowbase + row) * 2048 + ck * 8;         \
      tmp_[j] = ld_h8_coh(srcp);                                              \
    }                                                                         \
    _Pragma("unroll")                                                         \
    for (int j = 0; j < 16; ++j) {                                            \
      int linear = tid + 512 * j;                                             \
      int plane = linear >> 12;                                               \
      int rem = linear & 4095;                                                \
      int row = rem >> 8;                                                     \
      int ck  = rem & 255;                                                    \
      *(half8_t*)&hS[plane * HMOFF + row * SH + ck * 8] = tmp_[j];            \
    }                                                                         \
    __syncthreads(); }

#define SPLIT2(E, J) { float e_ = (E); _Float16 h1_ = (_Float16)e_;           \
  float r_ = e_ - (float)h1_; ah[J] = h1_; am[J] = (_Float16)(r_ * 2048.0f); }

#define PROD3(HA, MA) \
  HA = MFMA16(ah, bh0, HA);                                                   \
  MA = MFMA16(ah, bm0, MA);                                                   \
  MA = MFMA16(am, bh0, MA);

#define STAT_ADD(V, BUF) {                                                    \
    _Pragma("unroll")                                                         \
    for (int r = 0; r < 4; ++r) {                                             \
      float s = V[r];                                                         \
      float q = V[r]*V[r];                                                    \
      _Pragma("unroll")                                                       \
      for (int m = 1; m <= 8; m <<= 1) { s += __shfl_xor(s, m); q += __shfl_xor(q, m); } \
      if (c16 == 0) {                                                         \
        int row = rowbase + klo * 4 + r;                                      \
        atomicAdd(&stats[(repbase + (BUF)) * 256 + row * 2 + 0], s);          \
        atomicAdd(&stats[(repbase + (BUF)) * 256 + row * 2 + 1], q);          \
      }                                                                       \
    } }

// LN + LSTM cell. Stats read: lane c16 loads replica c16, shuffle-sum (16 reps).
#define CELL(V, BUF, CS, GC, BEC, HB) {                                       \
    _Pragma("unroll")                                                         \
    for (int r = 0; r < 4; ++r) {                                             \
      int row = rowbase + klo * 4 + r;                                        \
      const float* sp = stats + ((c16 << 2) + (BUF)) * 256 + row * 2;         \
      float s_ = ld_f_coh(sp), q_ = ld_f_coh(sp + 1);                         \
      _Pragma("unroll")                                                       \
      for (int m = 1; m <= 8; m <<= 1) { s_ += __shfl_xor(s_, m); q_ += __shfl_xor(q_, m); } \
      float mean = s_ * (1.0f / 4096.0f);                                     \
      float msq  = q_ * (1.0f / 4096.0f);                                     \
      float rstd = rsqrtf(msq - mean * mean + 1e-5f);                         \
      float gh = (V[r] - mean) * rstd * GC + BEC;                             \
      float fg = __shfl_down(gh, 4);                                          \
      float gg = __shfl_down(gh, 8);                                          \
      float og = __shfl_down(gh, 12);                                         \
      if (c16 < 4) {                                                          \
        float iv = sigm(gh), fv = sigm(fg), zv = tanh_fast(gg), ov = sigm(og); \
        float cc = fv * CS[r] + iv * zv;                                      \
        CS[r] = cc;                                                           \
        float hv = ov * tanh_fast(cc);                                        \
        int idx = row * 2048 + (HB) + cbase + c16;                            \
        _Float16 h1v = (_Float16)hv;                                          \
        st_h_coh(&hch[idx], h1v);                                             \
        st_h_coh(&hcm[idx], (_Float16)((hv - (float)h1v) * 2048.0f));         \
      }                                                                       \
    } }

  f32x4_t ahe, aho, ame, amo;     // layer-0 accumulators
  f32x4_t dhe, dho, dme, dmo;     // layer-1 accumulators
  f32x4_t a0, d0;

  // A0 split into X-part / H0-part so a pacing barrier can sit between them.
  // Per-chain kb order identical to r10/r11.
#define A0_X(TT) {                                                            \
    ahe = {0,0,0,0}; aho = {0,0,0,0}; ame = {0,0,0,0}; amo = {0,0,0,0};       \
    const float* xp = xbase + (size_t)(TT) * 512 + klo * 8;                   \
    _Pragma("unroll")                                                         \
    for (int ch = 0; ch < 4; ++ch) {                                          \
      float4 xv[8]; half8_t wa[4], wb[4];                                     \
      _Pragma("unroll")                                                       \
      for (int j = 0; j < 4; ++j) {                                           \
        xv[2*j]   = *(const float4*)(xp + (ch*4 + j) * 32);                   \
        xv[2*j+1] = *(const float4*)(xp + (ch*4 + j) * 32 + 4);               \
        wa[j] = *(const half8_t*)&w0a[(ch*4 + j) * 32 + klo * 8];             \
        wb[j] = *(const half8_t*)&w0b[(ch*4 + j) * 32 + klo * 8];             \
      }                                                                       \
      _Pragma("unroll")                                                       \
      for (int j = 0; j < 4; ++j) {                                           \
        half8_t ah, am;                                                       \
        SPLIT2(xv[2*j].x, 0) SPLIT2(xv[2*j].y, 1)                             \
        SPLIT2(xv[2*j].z, 2) SPLIT2(xv[2*j].w, 3)                             \
        SPLIT2(xv[2*j+1].x, 4) SPLIT2(xv[2*j+1].y, 5)                         \
        SPLIT2(xv[2*j+1].z, 6) SPLIT2(xv[2*j+1].w, 7)                         \
        half8_t bh0 = wa[j], bm0 = wb[j];                                     \
        if (((ch*4 + j) & 1) == 0) { PROD3(ahe, ame) } else { PROD3(aho, amo) } \
      }                                                                       \
    } }

#define A0_H0() {                                                             \
    _Pragma("unroll")                                                         \
    for (int ch = 0; ch < 4; ++ch) {                                          \
      half8_t wa[8], wb[8];                                                   \
      _Pragma("unroll")                                                       \
      for (int j = 0; j < 8; ++j) {                                           \
        wa[j] = *(const half8_t*)&w0a[512 + (ch*8 + j) * 32 + klo * 8];       \
        wb[j] = *(const half8_t*)&w0b[512 + (ch*8 + j) * 32 + klo * 8];       \
      }                                                                       \
      _Pragma("unroll")                                                       \
      for (int j = 0; j < 8; ++j) {                                           \
        int kb = ch*8 + j;                                                    \
        half8_t ah = *(const half8_t*)&hS[c16 * SH + kb * 32 + klo * 8];      \
        half8_t am = *(const half8_t*)&hS[HMOFF + c16 * SH + kb * 32 + klo * 8]; \
        half8_t bh0 = wa[j], bm0 = wb[j];                                     \
        if ((kb & 1) == 0) { PROD3(ahe, ame) } else { PROD3(aho, amo) }       \
      }                                                                       \
    }                                                                         \
    a0 = (ahe + aho) * 0.03125f + (ame + amo) * (1.0f / 65536.0f);            \
    _Pragma("unroll")                                                         \
    for (int r_ = 0; r_ < 4; ++r_) a0[r_] += b0v; }

  // ---------------- prologue: A0[0] (h planes are zeroed) ----------------
  STAGE_H();
  A0_X(0);
  A0_H0();
  STAT_ADD(a0, 0);
  gridbar(bars, wgid, tid, ++ep);
  CELL(a0, 0, c0s, g0v, be0v, 0);
  gridbar(bars, wgid, tid, ++ep);

  // ---------------- main loop ----------------
  for (int t = 0; t < 512; ++t) {
    const int par = t & 1;
    const int npar = 1 - par;

    // ===== alpha[t]: stage {h0[t], h1[t-1]}; A1[t] (+ A0[t+1]) =====
    STAGE_H();

    // H1: 64 kb, 8 chunks of 8 — pacing barrier at half-sweep (W1 slice is
    // 4.2 MB/XCD; pacing keeps the 8 mtile-sharers within one L2 window)
    dhe = {0,0,0,0}; dho = {0,0,0,0}; dme = {0,0,0,0}; dmo = {0,0,0,0};
    #pragma unroll
    for (int ch = 0; ch < 4; ++ch) {
      half8_t wa[8], wb[8];
      #pragma unroll
      for (int j = 0; j < 8; ++j) {
        wa[j] = *(const half8_t*)&w1a[(ch*8 + j) * 32 + klo * 8];
        wb[j] = *(const half8_t*)&w1b[(ch*8 + j) * 32 + klo * 8];
      }
      #pragma unroll
      for (int j = 0; j < 8; ++j) {
        int kb = ch*8 + j;
        half8_t ah = *(const half8_t*)&hS[c16 * SH + kb * 32 + klo * 8];
        half8_t am = *(const half8_t*)&hS[HMOFF + c16 * SH + kb * 32 + klo * 8];
        half8_t bh0 = wa[j], bm0 = wb[j];
        if ((kb & 1) == 0) { PROD3(dhe, dme) } else { PROD3(dho, dmo) }
      }
    }
    gridbar(bars, wgid, tid, ++ep);      // pace A (mid-W1)
    #pragma unroll
    for (int ch = 4; ch < 8; ++ch) {
      half8_t wa[8], wb[8];
      #pragma unroll
      for (int j = 0; j < 8; ++j) {
        wa[j] = *(const half8_t*)&w1a[(ch*8 + j) * 32 + klo * 8];
        wb[j] = *(const half8_t*)&w1b[(ch*8 + j) * 32 + klo * 8];
      }
      #pragma unroll
      for (int j = 0; j < 8; ++j) {
        int kb = ch*8 + j;
        half8_t ah = *(const half8_t*)&hS[c16 * SH + kb * 32 + klo * 8];
        half8_t am = *(const half8_t*)&hS[HMOFF + c16 * SH + kb * 32 + klo * 8];
        half8_t bh0 = wa[j], bm0 = wb[j];
        if ((kb & 1) == 0) { PROD3(dhe, dme) } else { PROD3(dho, dmo) }
      }
    }
    d0 = (dhe + dho) * 0.03125f + (dme + dmo) * (1.0f / 65536.0f);
    #pragma unroll
    for (int r = 0; r < 4; ++r) d0[r] += b1v;
    STAT_ADD(d0, 2 + par);
    gridbar(bars, wgid, tid, ++ep);      // pace B (post-W1, pre-W0)

    if (t < 511) {
      A0_X(t + 1);
      gridbar(bars, wgid, tid, ++ep);    // pace C (post-X, pre-H0) — grid-uniform branch
      A0_H0();
      STAT_ADD(a0, npar);
    }

    // zero the buffers alpha[t+1] will accumulate: 16 reps x 256 entries
    {
      int rep2 = ((wgid & 7) << 1) + (tid >> 8);
      int ent  = tid & 255;
      if (wgid < 8)       st_f_coh(&stats[((rep2 << 2) + 2 + npar) * 256 + ent], 0.0f);
      else if (wgid < 16) st_f_coh(&stats[((rep2 << 2) + par) * 256 + ent], 0.0f);
    }

    gridbar(bars, wgid, tid, ++ep);      // alpha-main
    // ===== beta[t]: B1[t] (+ B0[t+1]) =====
    CELL(d0, 2 + par, c1s, g1v, be1v, 1024);
    if (t < 511) {
      CELL(a0, npar, c0s, g0v, be0v, 0);
    }
    gridbar(bars, wgid, tid, ++ep);      // beta
  }

  // ---------------- final fc: out = h1 @ fcW + fcb ----------------
  {
    int gid = wgid * 512 + tid;          // 131072 threads; 65536 outputs
    if (gid < 65536) {
      int b = gid >> 9, o = gid & 511;
      const _Float16* p1 = hch + (size_t)b * 2048 + 1024;
      const _Float16* p2 = hcm + (size_t)b * 2048 + 1024;
      float s = fcb[o];
      #pragma unroll 4
      for (int k = 0; k < 1024; k += 4) {
        union { u64 q; _Float16 h[4]; } ua, um;
        ua.q = __hip_atomic_load((u64*)(p1 + k), __ATOMIC_RELAXED, __HIP_MEMORY_SCOPE_SYSTEM);
        um.q = __hip_atomic_load((u64*)(p2 + k), __ATOMIC_RELAXED, __HIP_MEMORY_SCOPE_SYSTEM);
        #pragma unroll
        for (int i = 0; i < 4; ++i) {
          float h = (float)ua.h[i] + (float)um.h[i] * (1.0f / 2048.0f);
          s = fmaf(h, fcW[(k + i) * 512 + o], s);
        }
      }
      out[gid] = s;
    }
  }
}

extern "C" void kernel_launch(void* const* d_in, const int* in_sizes, int n_in,
                              void* d_out, int out_size, void* d_ws, size_t ws_size,
                              hipStream_t stream) {
  const float* x   = (const float*)d_in[0];
  const float* W0  = (const float*)d_in[1];
  const float* b0  = (const float*)d_in[2];
  const float* g0  = (const float*)d_in[3];
  const float* be0 = (const float*)d_in[4];
  const float* W1  = (const float*)d_in[5];
  const float* b1  = (const float*)d_in[6];
  const float* g1  = (const float*)d_in[7];
  const float* be1 = (const float*)d_in[8];
  const float* fcW = (const float*)d_in[9];
  const float* fcb = (const float*)d_in[10];
  float* out = (float*)d_out;

  char* ws = (char*)d_ws;
  _Float16* W0a  = (_Float16*)(ws);
  _Float16* W0b  = (_Float16*)(ws + 12582912);
  _Float16* W1a  = (_Float16*)(ws + 25165824);
  _Float16* W1b  = (_Float16*)(ws + 41943040);
  float* vecs    = (float*)(ws + 58720256);
  _Float16* hch  = (_Float16*)(ws + 58818560);
  _Float16* hcm  = (_Float16*)(ws + 59342848);
  float* stats   = (float*)(ws + 59867136);
  unsigned* bars = (unsigned*)(ws + 59932672);

  // re-zero h planes + stats + barrier state every call (graph replays reuse ws)
  hipMemsetAsync(hch, 0, 524288 + 524288 + 65536 + 8192, stream);
  lstm_prep<<<7264, 256, 0, stream>>>(W0, W1, b0, g0, be0, b1, g1, be1,
                                      W0a, W0b, W1a, W1b, vecs);

  hipFuncSetAttribute((const void*)lstm_seq,
                      hipFuncAttributeMaxDynamicSharedMemorySize, LDS_BYTES);
  void* args[] = { (void*)&x, (void*)&W0a, (void*)&W0b, (void*)&W1a, (void*)&W1b,
                   (void*)&vecs, (void*)&hch, (void*)&hcm,
                   (void*)&stats, (void*)&bars,
                   (void*)&fcW, (void*)&fcb, (void*)&out };
  hipError_t lerr = hipLaunchCooperativeKernel((const void*)lstm_seq,
                                               dim3(256), dim3(512),
                                               args, LDS_BYTES, stream);
  if (lerr != hipSuccess) {
    // coop validator rejected (>64KB-LDS occupancy calc). Grid=256 = #CUs at
    // 1 WG/CU -> co-residency capacity-guaranteed; plain launch + own barrier.
    (void)hipGetLastError();
    lstm_seq<<<dim3(256), dim3(512), LDS_BYTES, stream>>>(
        x, W0a, W0b, W1a, W1b, vecs, hch, hcm, stats, bars, fcW, fcb, out);
  }
}

// Round 13
// 37857.159 us; speedup vs baseline: 1.7933x; 1.7933x over previous
//
#include <hip/hip_runtime.h>
#include <hip/hip_bf16.h>

typedef __attribute__((ext_vector_type(8))) _Float16 half8_t;
typedef __attribute__((ext_vector_type(4))) float f32x4_t;
typedef unsigned long long u64;

#define SH 2056                       // LDS h row stride (elems): 2048 + 8
#define HMOFF (16 * SH)               // plane-2 offset (elems)
#define LDS_BYTES (2 * 16 * SH * 2)   // 131,584 B -> 1 WG/CU, 8 waves = 2/SIMD

__device__ __forceinline__ float sigm(float z) { return 1.0f / (1.0f + __expf(-z)); }
__device__ __forceinline__ float tanh_fast(float z) {
  float e = __expf(2.0f * z);
  return 1.0f - 2.0f / (e + 1.0f);
}

// ---- coherent (cross-XCD) access helpers
__device__ __forceinline__ half8_t ld_h8_coh(const _Float16* p) {
  union { half8_t h; u64 q[2]; } r;
  u64* q = (u64*)p;
  r.q[0] = __hip_atomic_load(q,     __ATOMIC_RELAXED, __HIP_MEMORY_SCOPE_SYSTEM);
  r.q[1] = __hip_atomic_load(q + 1, __ATOMIC_RELAXED, __HIP_MEMORY_SCOPE_SYSTEM);
  return r.h;
}
__device__ __forceinline__ void st_h_coh(_Float16* p, _Float16 v) {
  unsigned short b = __builtin_bit_cast(unsigned short, v);
  __hip_atomic_store((unsigned short*)p, b, __ATOMIC_RELAXED, __HIP_MEMORY_SCOPE_SYSTEM);
}
__device__ __forceinline__ float ld_f_coh(const float* p) {
  return __hip_atomic_load((float*)p, __ATOMIC_RELAXED, __HIP_MEMORY_SCOPE_SYSTEM);
}
__device__ __forceinline__ void st_f_coh(float* p, float v) {
  __hip_atomic_store(p, v, __ATOMIC_RELAXED, __HIP_MEMORY_SCOPE_SYSTEM);
}

// ws layout (bytes) — total 59,940,864 (identical to r10, known-good):
//   W0a  @ 0         : 12582912   (fp16 plane1 = fp16(32*w), [gp][k])
//   W0b  @ 12582912  : 12582912
//   W1a  @ 25165824  : 16777216
//   W1b  @ 41943040  : 16777216
//   vecs @ 58720256  : 98304
//   hch  @ 58818560  : 524288     (h plane1 fp16, [row][h0|h1])
//   hcm  @ 59342848  : 524288     (h plane2 fp16, residual*2048)
//   stats@ 59867136  : 65536      (16 reps x 4 bufs x 256 f32)
//   bars @ 59932672  : 8192

// permutation (128-col WG groups): gp = colgrp*128 + w*16 + c,
//   gate = c>>2, uo = c&3 ; gcol = gate*1024 + colgrp*32 + w*4 + uo
__global__ void lstm_prep(const float* __restrict__ W0, const float* __restrict__ W1,
                          const float* __restrict__ b0, const float* __restrict__ g0,
                          const float* __restrict__ be0, const float* __restrict__ b1,
                          const float* __restrict__ g1, const float* __restrict__ be1,
                          _Float16* __restrict__ W0a, _Float16* __restrict__ W0b,
                          _Float16* __restrict__ W1a, _Float16* __restrict__ W1b,
                          float* __restrict__ vecs)
{
  int gid = blockIdx.x * 256 + threadIdx.x;
  const int W0N = 192 * 4096;
  const int W1N = 256 * 4096;
  if (gid < W0N) {
    int k8 = gid >> 12, gp = gid & 4095;
    int colgrp = gp >> 7, w = (gp >> 4) & 7, c = gp & 15;
    int gcol = ((c >> 2) << 10) + (colgrp << 5) + (w << 2) + (c & 3);
    half8_t va, vb;
    #pragma unroll
    for (int j = 0; j < 8; ++j) {
      float w32 = W0[(size_t)(k8 * 8 + j) * 4096 + gcol] * 32.0f;
      _Float16 p1 = (_Float16)w32;
      float r = w32 - (float)p1;
      va[j] = p1; vb[j] = (_Float16)(r * 2048.0f);
    }
    *(half8_t*)&W0a[(size_t)gp * 1536 + k8 * 8] = va;
    *(half8_t*)&W0b[(size_t)gp * 1536 + k8 * 8] = vb;
  } else if (gid < W0N + W1N) {
    int g2 = gid - W0N;
    int k8 = g2 >> 12, gp = g2 & 4095;
    int colgrp = gp >> 7, w = (gp >> 4) & 7, c = gp & 15;
    int gcol = ((c >> 2) << 10) + (colgrp << 5) + (w << 2) + (c & 3);
    half8_t va, vb;
    #pragma unroll
    for (int j = 0; j < 8; ++j) {
      float w32 = W1[(size_t)(k8 * 8 + j) * 4096 + gcol] * 32.0f;
      _Float16 p1 = (_Float16)w32;
      float r = w32 - (float)p1;
      va[j] = p1; vb[j] = (_Float16)(r * 2048.0f);
    }
    *(half8_t*)&W1a[(size_t)gp * 2048 + k8 * 8] = va;
    *(half8_t*)&W1b[(size_t)gp * 2048 + k8 * 8] = vb;
  } else if (gid < W0N + W1N + 6 * 4096) {
    int g2 = gid - W0N - W1N;
    int j = g2 >> 12, gp = g2 & 4095;
    int colgrp = gp >> 7, w = (gp >> 4) & 7, c = gp & 15;
    int gcol = ((c >> 2) << 10) + (colgrp << 5) + (w << 2) + (c & 3);
    const float* src = (j == 0) ? b0 : (j == 1) ? g0 : (j == 2) ? be0
                     : (j == 3) ? b1 : (j == 4) ? g1 : be1;
    vecs[j * 4096 + gp] = src[gcol];
  }
}

#define MFMA16(A, B, C) __builtin_amdgcn_mfma_f32_16x16x32_f16(A, B, C, 0, 0, 0)

// ---- fence-free grid barrier, 256 arrivals (r7-proven 8x32 structure)
__device__ __forceinline__ void gridbar(unsigned* bars, int wgid, int tid, unsigned ep) {
  __syncthreads();
  if (tid == 0) {
    const int q = ep & 1;
    unsigned old = __hip_atomic_fetch_add(&bars[(q * 8 + (wgid & 7)) * 32], 1u,
                                          __ATOMIC_RELAXED, __HIP_MEMORY_SCOPE_AGENT);
    if (old == 31u) {
      unsigned mo = __hip_atomic_fetch_add(&bars[512 + q * 32], 1u,
                                           __ATOMIC_RELAXED, __HIP_MEMORY_SCOPE_AGENT);
      if (mo == 7u) {
        #pragma unroll
        for (int g = 0; g < 8; ++g)
          __hip_atomic_store(&bars[(q * 8 + g) * 32], 0u, __ATOMIC_RELAXED, __HIP_MEMORY_SCOPE_SYSTEM);
        __hip_atomic_store(&bars[512 + q * 32], 0u, __ATOMIC_RELAXED, __HIP_MEMORY_SCOPE_SYSTEM);
        __hip_atomic_store(&bars[576], ep, __ATOMIC_RELEASE, __HIP_MEMORY_SCOPE_SYSTEM);
      }
    }
    while (__hip_atomic_load(&bars[576], __ATOMIC_RELAXED, __HIP_MEMORY_SCOPE_SYSTEM) < ep) {}
  }
  __syncthreads();
}

// 256 WGs x 512 thr. WG = (mtile = wgid>>5, colgrp = wgid&31); wave wid = 16-col
// tile. r10 structure + ASYNC-STAGE split: stage loads issued before the
// h-independent A0 X-part, committed to LDS after (hides coherent latency).
__global__ void __launch_bounds__(512, 2) lstm_seq(
    const float* __restrict__ x,
    const _Float16* __restrict__ W0ap,
    const _Float16* __restrict__ W0bp,
    const _Float16* __restrict__ W1ap,
    const _Float16* __restrict__ W1bp,
    const float* __restrict__ vecs,
    _Float16* __restrict__ hch,
    _Float16* __restrict__ hcm,
    float* __restrict__ stats,
    unsigned* __restrict__ bars,
    const float* __restrict__ fcW,
    const float* __restrict__ fcb,
    float* __restrict__ out)
{
  extern __shared__ _Float16 hS[];    // [2 planes][16 rows][SH]
  const int tid = threadIdx.x;
  const int wgid = blockIdx.x;
  const int mtile = wgid >> 5;         // 0..7
  const int colgrp = wgid & 31;        // 0..31 (128-col group)
  const int wid = tid >> 6;            // 0..7 = 16-col tile
  const int lane = tid & 63;
  const int c16 = lane & 15;
  const int klo = lane >> 4;
  const int rowbase = mtile * 16;

  const int gp = colgrp * 128 + wid * 16 + c16;
  const float b0v  = vecs[gp];
  const float g0v  = vecs[4096 + gp];
  const float be0v = vecs[8192 + gp];
  const float b1v  = vecs[12288 + gp];
  const float g1v  = vecs[16384 + gp];
  const float be1v = vecs[20480 + gp];

  const int arow = rowbase + c16;
  const float* xbase = x + (size_t)arow * 512 * 512; // x[row][t][d]
  const _Float16* w0a = W0ap + (size_t)gp * 1536;
  const _Float16* w0b = W0bp + (size_t)gp * 1536;
  const _Float16* w1a = W1ap + (size_t)gp * 2048;
  const _Float16* w1b = W1bp + (size_t)gp * 2048;
  const int repbase = (wgid & 15) << 2;              // rep*4 for stats writes
  const int cbase = colgrp * 32 + wid * 4;           // h-unit base for this wave

  float c0s[4] = {0,0,0,0};
  float c1s[4] = {0,0,0,0};
  unsigned ep = 0;
  half8_t stg[16];                    // in-flight stage registers

// issue this WG's 16 h-row loads (both planes) into stg[] — no waits here
#define STAGE_ISSUE() {                                                       \
    _Pragma("unroll")                                                         \
    for (int j = 0; j < 16; ++j) {                                            \
      int linear = tid + 512 * j;                                             \
      int plane = linear >> 12;                                               \
      int rem = linear & 4095;                                                \
      int row = rem >> 8;                                                     \
      int ck  = rem & 255;                                                    \
      const _Float16* srcp = (plane ? hcm : hch)                              \
                           + (size_t)(rowbase + row) * 2048 + ck * 8;         \
      stg[j] = ld_h8_coh(srcp);                                               \
    } }

// write stg[] -> LDS and sync (compiler inserts the vmcnt waits at first use)
#define STAGE_COMMIT() {                                                      \
    _Pragma("unroll")                                                         \
    for (int j = 0; j < 16; ++j) {                                            \
      int linear = tid + 512 * j;                                             \
      int plane = linear >> 12;                                               \
      int rem = linear & 4095;                                                \
      int row = rem >> 8;                                                     \
      int ck  = rem & 255;                                                    \
      *(half8_t*)&hS[plane * HMOFF + row * SH + ck * 8] = stg[j];             \
    }                                                                         \
    __syncthreads(); }

#define SPLIT2(E, J) { float e_ = (E); _Float16 h1_ = (_Float16)e_;           \
  float r_ = e_ - (float)h1_; ah[J] = h1_; am[J] = (_Float16)(r_ * 2048.0f); }

#define PROD3(HA, MA) \
  HA = MFMA16(ah, bh0, HA);                                                   \
  MA = MFMA16(ah, bm0, MA);                                                   \
  MA = MFMA16(am, bh0, MA);

#define X_BODY(KB, HA, MA) {                                                  \
      float4 xu = *(const float4*)(xp + (KB) * 32);                           \
      float4 xw = *(const float4*)(xp + (KB) * 32 + 4);                       \
      half8_t ah, am;                                                         \
      SPLIT2(xu.x, 0) SPLIT2(xu.y, 1) SPLIT2(xu.z, 2) SPLIT2(xu.w, 3)         \
      SPLIT2(xw.x, 4) SPLIT2(xw.y, 5) SPLIT2(xw.z, 6) SPLIT2(xw.w, 7)         \
      half8_t bh0 = *(const half8_t*)&w0a[(KB) * 32 + klo * 8];               \
      half8_t bm0 = *(const half8_t*)&w0b[(KB) * 32 + klo * 8];               \
      PROD3(HA, MA) }

#define H0_BODY(KB, HA, MA) {                                                 \
      half8_t ah = *(const half8_t*)&hS[c16 * SH + (KB) * 32 + klo * 8];      \
      half8_t am = *(const half8_t*)&hS[HMOFF + c16 * SH + (KB) * 32 + klo * 8]; \
      half8_t bh0 = *(const half8_t*)&w0a[512 + (KB) * 32 + klo * 8];         \
      half8_t bm0 = *(const half8_t*)&w0b[512 + (KB) * 32 + klo * 8];         \
      PROD3(HA, MA) }

#define H1_BODY(KB, HA, MA) {                                                 \
      half8_t ah = *(const half8_t*)&hS[c16 * SH + (KB) * 32 + klo * 8];      \
      half8_t am = *(const half8_t*)&hS[HMOFF + c16 * SH + (KB) * 32 + klo * 8]; \
      half8_t bh0 = *(const half8_t*)&w1a[(KB) * 32 + klo * 8];               \
      half8_t bm0 = *(const half8_t*)&w1b[(KB) * 32 + klo * 8];               \
      PROD3(HA, MA) }

#define STAT_ADD(V, BUF) {                                                    \
    _Pragma("unroll")                                                         \
    for (int r = 0; r < 4; ++r) {                                             \
      float s = V[r];                                                         \
      float q = V[r]*V[r];                                                    \
      _Pragma("unroll")                                                       \
      for (int m = 1; m <= 8; m <<= 1) { s += __shfl_xor(s, m); q += __shfl_xor(q, m); } \
      if (c16 == 0) {                                                         \
        int row = rowbase + klo * 4 + r;                                      \
        atomicAdd(&stats[(repbase + (BUF)) * 256 + row * 2 + 0], s);          \
        atomicAdd(&stats[(repbase + (BUF)) * 256 + row * 2 + 1], q);          \
      }                                                                       \
    } }

// LN + LSTM cell. Stats read: lane c16 loads replica c16, shuffle-sum (16 reps).
#define CELL(V, BUF, CS, GC, BEC, HB) {                                       \
    _Pragma("unroll")                                                         \
    for (int r = 0; r < 4; ++r) {                                             \
      int row = rowbase + klo * 4 + r;                                        \
      const float* sp = stats + ((c16 << 2) + (BUF)) * 256 + row * 2;         \
      float s_ = ld_f_coh(sp), q_ = ld_f_coh(sp + 1);                         \
      _Pragma("unroll")                                                       \
      for (int m = 1; m <= 8; m <<= 1) { s_ += __shfl_xor(s_, m); q_ += __shfl_xor(q_, m); } \
      float mean = s_ * (1.0f / 4096.0f);                                     \
      float msq  = q_ * (1.0f / 4096.0f);                                     \
      float rstd = rsqrtf(msq - mean * mean + 1e-5f);                         \
      float gh = (V[r] - mean) * rstd * GC + BEC;                             \
      float fg = __shfl_down(gh, 4);                                          \
      float gg = __shfl_down(gh, 8);                                          \
      float og = __shfl_down(gh, 12);                                         \
      if (c16 < 4) {                                                          \
        float iv = sigm(gh), fv = sigm(fg), zv = tanh_fast(gg), ov = sigm(og); \
        float cc = fv * CS[r] + iv * zv;                                      \
        CS[r] = cc;                                                           \
        float hv = ov * tanh_fast(cc);                                        \
        int idx = row * 2048 + (HB) + cbase + c16;                            \
        _Float16 h1v = (_Float16)hv;                                          \
        st_h_coh(&hch[idx], h1v);                                             \
        st_h_coh(&hcm[idx], (_Float16)((hv - (float)h1v) * 2048.0f));         \
      }                                                                       \
    } }

  f32x4_t ahe, aho, ame, amo;     // layer-0 accumulators
  f32x4_t dhe, dho, dme, dmo;     // layer-1 accumulators
  f32x4_t a0, d0;

  // A0 X-part (h-independent; zeroes the a-chains). kb order = r10 per chain.
#define A0_X(TT) {                                                            \
    ahe = {0,0,0,0}; aho = {0,0,0,0}; ame = {0,0,0,0}; amo = {0,0,0,0};       \
    const float* xp = xbase + (size_t)(TT) * 512 + klo * 8;                   \
    _Pragma("unroll 2")                                                       \
    for (int kb = 0; kb < 16; kb += 2) {                                      \
      X_BODY(kb,     ahe, ame);                                               \
      X_BODY(kb + 1, aho, amo);                                               \
    } }

  // A0 H0-part (reads staged h from LDS) + combine + bias
#define A0_H0() {                                                             \
    _Pragma("unroll 2")                                                       \
    for (int kb = 0; kb < 32; kb += 2) {                                      \
      H0_BODY(kb,     ahe, ame);                                              \
      H0_BODY(kb + 1, aho, amo);                                              \
    }                                                                         \
    a0 = (ahe + aho) * 0.03125f + (ame + amo) * (1.0f / 65536.0f);            \
    _Pragma("unroll")                                                         \
    for (int r_ = 0; r_ < 4; ++r_) a0[r_] += b0v; }

  // ---------------- prologue: A0[0] (h planes are zeroed) ----------------
  STAGE_ISSUE();
  STAGE_COMMIT();
  A0_X(0);
  A0_H0();
  STAT_ADD(a0, 0);
  gridbar(bars, wgid, tid, ++ep);
  CELL(a0, 0, c0s, g0v, be0v, 0);
  gridbar(bars, wgid, tid, ++ep);

  // ---------------- main loop ----------------
  for (int t = 0; t < 512; ++t) {
    const int par = t & 1;
    const int npar = 1 - par;

    // ===== alpha[t]: async stage {h0[t], h1[t-1]} under A0_X(t+1) =====
    STAGE_ISSUE();                 // coherent loads in flight...
    if (t < 511) {
      A0_X(t + 1);                 // ...hidden under h-independent X-part
    }
    STAGE_COMMIT();                // drain + LDS write + syncthreads

    // H1: r10's shallow per-kb pattern (FETCH-clean)
    dhe = {0,0,0,0}; dho = {0,0,0,0}; dme = {0,0,0,0}; dmo = {0,0,0,0};
    #pragma unroll 2
    for (int kb = 0; kb < 64; kb += 2) {
      H1_BODY(kb,     dhe, dme);
      H1_BODY(kb + 1, dho, dmo);
    }
    d0 = (dhe + dho) * 0.03125f + (dme + dmo) * (1.0f / 65536.0f);
    #pragma unroll
    for (int r = 0; r < 4; ++r) d0[r] += b1v;
    STAT_ADD(d0, 2 + par);

    if (t < 511) {
      A0_H0();
      STAT_ADD(a0, npar);
    }

    // zero the buffers alpha[t+1] will accumulate: 16 reps x 256 entries
    {
      int rep2 = ((wgid & 7) << 1) + (tid >> 8);
      int ent  = tid & 255;
      if (wgid < 8)       st_f_coh(&stats[((rep2 << 2) + 2 + npar) * 256 + ent], 0.0f);
      else if (wgid < 16) st_f_coh(&stats[((rep2 << 2) + par) * 256 + ent], 0.0f);
    }

    gridbar(bars, wgid, tid, ++ep);

    // ===== beta[t]: B1[t] (+ B0[t+1]) =====
    CELL(d0, 2 + par, c1s, g1v, be1v, 1024);
    if (t < 511) {
      CELL(a0, npar, c0s, g0v, be0v, 0);
    }
    gridbar(bars, wgid, tid, ++ep);
  }

  // ---------------- final fc: out = h1 @ fcW + fcb ----------------
  {
    int gid = wgid * 512 + tid;        // 131072 threads; 65536 outputs
    if (gid < 65536) {
      int b = gid >> 9, o = gid & 511;
      const _Float16* p1 = hch + (size_t)b * 2048 + 1024;
      const _Float16* p2 = hcm + (size_t)b * 2048 + 1024;
      float s = fcb[o];
      #pragma unroll 4
      for (int k = 0; k < 1024; k += 4) {
        union { u64 q; _Float16 h[4]; } ua, um;
        ua.q = __hip_atomic_load((u64*)(p1 + k), __ATOMIC_RELAXED, __HIP_MEMORY_SCOPE_SYSTEM);
        um.q = __hip_atomic_load((u64*)(p2 + k), __ATOMIC_RELAXED, __HIP_MEMORY_SCOPE_SYSTEM);
        #pragma unroll
        for (int i = 0; i < 4; ++i) {
          float h = (float)ua.h[i] + (float)um.h[i] * (1.0f / 2048.0f);
          s = fmaf(h, fcW[(k + i) * 512 + o], s);
        }
      }
      out[gid] = s;
    }
  }
}

extern "C" void kernel_launch(void* const* d_in, const int* in_sizes, int n_in,
                              void* d_out, int out_size, void* d_ws, size_t ws_size,
                              hipStream_t stream) {
  const float* x   = (const float*)d_in[0];
  const float* W0  = (const float*)d_in[1];
  const float* b0  = (const float*)d_in[2];
  const float* g0  = (const float*)d_in[3];
  const float* be0 = (const float*)d_in[4];
  const float* W1  = (const float*)d_in[5];
  const float* b1  = (const float*)d_in[6];
  const float* g1  = (const float*)d_in[7];
  const float* be1 = (const float*)d_in[8];
  const float* fcW = (const float*)d_in[9];
  const float* fcb = (const float*)d_in[10];
  float* out = (float*)d_out;

  char* ws = (char*)d_ws;
  _Float16* W0a  = (_Float16*)(ws);
  _Float16* W0b  = (_Float16*)(ws + 12582912);
  _Float16* W1a  = (_Float16*)(ws + 25165824);
  _Float16* W1b  = (_Float16*)(ws + 41943040);
  float* vecs    = (float*)(ws + 58720256);
  _Float16* hch  = (_Float16*)(ws + 58818560);
  _Float16* hcm  = (_Float16*)(ws + 59342848);
  float* stats   = (float*)(ws + 59867136);
  unsigned* bars = (unsigned*)(ws + 59932672);

  // re-zero h planes + stats + barrier state every call (graph replays reuse ws)
  hipMemsetAsync(hch, 0, 524288 + 524288 + 65536 + 8192, stream);
  lstm_prep<<<7264, 256, 0, stream>>>(W0, W1, b0, g0, be0, b1, g1, be1,
                                      W0a, W0b, W1a, W1b, vecs);

  hipFuncSetAttribute((const void*)lstm_seq,
                      hipFuncAttributeMaxDynamicSharedMemorySize, LDS_BYTES);
  void* args[] = { (void*)&x, (void*)&W0a, (void*)&W0b, (void*)&W1a, (void*)&W1b,
                   (void*)&vecs, (void*)&hch, (void*)&hcm,
                   (void*)&stats, (void*)&bars,
                   (void*)&fcW, (void*)&fcb, (void*)&out };
  hipError_t lerr = hipLaunchCooperativeKernel((const void*)lstm_seq,
                                               dim3(256), dim3(512),
                                               args, LDS_BYTES, stream);
  if (lerr != hipSuccess) {
    // coop validator rejected (>64KB-LDS occupancy calc). Grid=256 = #CUs at
    // 1 WG/CU -> co-residency capacity-guaranteed; plain launch + own barrier.
    (void)hipGetLastError();
    lstm_seq<<<dim3(256), dim3(512), LDS_BYTES, stream>>>(
        x, W0a, W0b, W1a, W1b, vecs, hch, hcm, stats, bars, fcW, fcb, out);
  }
}

// Round 14
// 36769.424 us; speedup vs baseline: 1.8464x; 1.0296x over previous
//
#include <hip/hip_runtime.h>
#include <hip/hip_bf16.h>

typedef __attribute__((ext_vector_type(8))) _Float16 half8_t;
typedef __attribute__((ext_vector_type(4))) float f32x4_t;
typedef unsigned long long u64;

#define SH 2056                       // LDS h row stride (elems): 2048 + 8
#define HMOFF (16 * SH)               // plane-2 offset (elems)
#define LDS_BYTES (2 * 16 * SH * 2)   // 131,584 B -> 1 WG/CU, 8 waves = 2/SIMD

__device__ __forceinline__ float sigm(float z) { return 1.0f / (1.0f + __expf(-z)); }
__device__ __forceinline__ float tanh_fast(float z) {
  float e = __expf(2.0f * z);
  return 1.0f - 2.0f / (e + 1.0f);
}

// ---- coherent (cross-XCD) access helpers
__device__ __forceinline__ half8_t ld_h8_coh(const _Float16* p) {
  union { half8_t h; u64 q[2]; } r;
  u64* q = (u64*)p;
  r.q[0] = __hip_atomic_load(q,     __ATOMIC_RELAXED, __HIP_MEMORY_SCOPE_SYSTEM);
  r.q[1] = __hip_atomic_load(q + 1, __ATOMIC_RELAXED, __HIP_MEMORY_SCOPE_SYSTEM);
  return r.h;
}
__device__ __forceinline__ void st_h_coh(_Float16* p, _Float16 v) {
  unsigned short b = __builtin_bit_cast(unsigned short, v);
  __hip_atomic_store((unsigned short*)p, b, __ATOMIC_RELAXED, __HIP_MEMORY_SCOPE_SYSTEM);
}
__device__ __forceinline__ float ld_f_coh(const float* p) {
  return __hip_atomic_load((float*)p, __ATOMIC_RELAXED, __HIP_MEMORY_SCOPE_SYSTEM);
}
__device__ __forceinline__ void st_f_coh(float* p, float v) {
  __hip_atomic_store(p, v, __ATOMIC_RELAXED, __HIP_MEMORY_SCOPE_SYSTEM);
}

// ws layout (bytes) — total 59,940,864 (identical to r10/r13, known-good):
//   W0a  @ 0         : 12582912   (fp16 plane1 = fp16(32*w), [gp][k])
//   W0b  @ 12582912  : 12582912
//   W1a  @ 25165824  : 16777216
//   W1b  @ 41943040  : 16777216
//   vecs @ 58720256  : 98304
//   hch  @ 58818560  : 524288     (h plane1 fp16, [row][h0|h1])
//   hcm  @ 59342848  : 524288     (h plane2 fp16, residual*2048)
//   stats@ 59867136  : 65536      (16 reps x 4 bufs x 256 f32)
//   bars @ 59932672  : 8192       (per-group counters + release flags)

// permutation (128-col WG groups): gp = colgrp*128 + w*16 + c,
//   gate = c>>2, uo = c&3 ; gcol = gate*1024 + colgrp*32 + w*4 + uo
__global__ void lstm_prep(const float* __restrict__ W0, const float* __restrict__ W1,
                          const float* __restrict__ b0, const float* __restrict__ g0,
                          const float* __restrict__ be0, const float* __restrict__ b1,
                          const float* __restrict__ g1, const float* __restrict__ be1,
                          _Float16* __restrict__ W0a, _Float16* __restrict__ W0b,
                          _Float16* __restrict__ W1a, _Float16* __restrict__ W1b,
                          float* __restrict__ vecs)
{
  int gid = blockIdx.x * 256 + threadIdx.x;
  const int W0N = 192 * 4096;
  const int W1N = 256 * 4096;
  if (gid < W0N) {
    int k8 = gid >> 12, gp = gid & 4095;
    int colgrp = gp >> 7, w = (gp >> 4) & 7, c = gp & 15;
    int gcol = ((c >> 2) << 10) + (colgrp << 5) + (w << 2) + (c & 3);
    half8_t va, vb;
    #pragma unroll
    for (int j = 0; j < 8; ++j) {
      float w32 = W0[(size_t)(k8 * 8 + j) * 4096 + gcol] * 32.0f;
      _Float16 p1 = (_Float16)w32;
      float r = w32 - (float)p1;
      va[j] = p1; vb[j] = (_Float16)(r * 2048.0f);
    }
    *(half8_t*)&W0a[(size_t)gp * 1536 + k8 * 8] = va;
    *(half8_t*)&W0b[(size_t)gp * 1536 + k8 * 8] = vb;
  } else if (gid < W0N + W1N) {
    int g2 = gid - W0N;
    int k8 = g2 >> 12, gp = g2 & 4095;
    int colgrp = gp >> 7, w = (gp >> 4) & 7, c = gp & 15;
    int gcol = ((c >> 2) << 10) + (colgrp << 5) + (w << 2) + (c & 3);
    half8_t va, vb;
    #pragma unroll
    for (int j = 0; j < 8; ++j) {
      float w32 = W1[(size_t)(k8 * 8 + j) * 4096 + gcol] * 32.0f;
      _Float16 p1 = (_Float16)w32;
      float r = w32 - (float)p1;
      va[j] = p1; vb[j] = (_Float16)(r * 2048.0f);
    }
    *(half8_t*)&W1a[(size_t)gp * 2048 + k8 * 8] = va;
    *(half8_t*)&W1b[(size_t)gp * 2048 + k8 * 8] = vb;
  } else if (gid < W0N + W1N + 6 * 4096) {
    int g2 = gid - W0N - W1N;
    int j = g2 >> 12, gp = g2 & 4095;
    int colgrp = gp >> 7, w = (gp >> 4) & 7, c = gp & 15;
    int gcol = ((c >> 2) << 10) + (colgrp << 5) + (w << 2) + (c & 3);
    const float* src = (j == 0) ? b0 : (j == 1) ? g0 : (j == 2) ? be0
                     : (j == 3) ? b1 : (j == 4) ? g1 : be1;
    vecs[j * 4096 + gp] = src[gcol];
  }
}

#define MFMA16(A, B, C) __builtin_amdgcn_mfma_f32_16x16x32_f16(A, B, C, 0, 0, 0)

// ---- GROUP-LOCAL barrier: 32 arrivals (one mtile group). The dataflow
// decomposes per mtile (LN is per-row; h rows feed only their own rows), so
// the 8 groups never need to sync with each other. Epoch-parity counters.
__device__ __forceinline__ void groupbar(unsigned* bars, int grp, int tid, unsigned ep) {
  __syncthreads();
  if (tid == 0) {
    const int q = ep & 1;
    unsigned old = __hip_atomic_fetch_add(&bars[(grp * 2 + q) * 32], 1u,
                                          __ATOMIC_RELAXED, __HIP_MEMORY_SCOPE_AGENT);
    if (old == 31u) {
      __hip_atomic_store(&bars[(grp * 2 + q) * 32], 0u, __ATOMIC_RELAXED, __HIP_MEMORY_SCOPE_SYSTEM);
      __hip_atomic_store(&bars[1024 + grp * 32], ep, __ATOMIC_RELEASE, __HIP_MEMORY_SCOPE_SYSTEM);
    }
    while (__hip_atomic_load(&bars[1024 + grp * 32], __ATOMIC_RELAXED, __HIP_MEMORY_SCOPE_SYSTEM) < ep) {}
  }
  __syncthreads();
}

// 256 WGs x 512 thr. WG = (mtile = wgid>>5, colgrp = wgid&31); wave wid = 16-col
// tile. h staged in LDS per step (async split). H1 + A0_H0 FUSED (2 independent
// load streams -> ~2x MLP without r11's burst thrash). Barriers group-local.
__global__ void __launch_bounds__(512, 2) lstm_seq(
    const float* __restrict__ x,
    const _Float16* __restrict__ W0ap,
    const _Float16* __restrict__ W0bp,
    const _Float16* __restrict__ W1ap,
    const _Float16* __restrict__ W1bp,
    const float* __restrict__ vecs,
    _Float16* __restrict__ hch,
    _Float16* __restrict__ hcm,
    float* __restrict__ stats,
    unsigned* __restrict__ bars,
    const float* __restrict__ fcW,
    const float* __restrict__ fcb,
    float* __restrict__ out)
{
  extern __shared__ _Float16 hS[];    // [2 planes][16 rows][SH]
  const int tid = threadIdx.x;
  const int wgid = blockIdx.x;
  const int mtile = wgid >> 5;         // 0..7 = group
  const int colgrp = wgid & 31;        // 0..31 (128-col group)
  const int wid = tid >> 6;            // 0..7 = 16-col tile
  const int lane = tid & 63;
  const int c16 = lane & 15;
  const int klo = lane >> 4;
  const int rowbase = mtile * 16;

  const int gp = colgrp * 128 + wid * 16 + c16;
  const float b0v  = vecs[gp];
  const float g0v  = vecs[4096 + gp];
  const float be0v = vecs[8192 + gp];
  const float b1v  = vecs[12288 + gp];
  const float g1v  = vecs[16384 + gp];
  const float be1v = vecs[20480 + gp];

  const int arow = rowbase + c16;
  const float* xbase = x + (size_t)arow * 512 * 512; // x[row][t][d]
  const _Float16* w0a = W0ap + (size_t)gp * 1536;
  const _Float16* w0b = W0bp + (size_t)gp * 1536;
  const _Float16* w1a = W1ap + (size_t)gp * 2048;
  const _Float16* w1b = W1bp + (size_t)gp * 2048;
  const int repbase = (colgrp & 15) << 2;            // rep*4 for stats writes
  const int cbase = colgrp * 32 + wid * 4;           // h-unit base for this wave

  float c0s[4] = {0,0,0,0};
  float c1s[4] = {0,0,0,0};
  unsigned ep = 0;
  half8_t stg[16];                    // in-flight stage registers

// issue this WG's 16 h-row loads (both planes) into stg[] — no waits here
#define STAGE_ISSUE() {                                                       \
    _Pragma("unroll")                                                         \
    for (int j = 0; j < 16; ++j) {                                            \
      int linear = tid + 512 * j;                                             \
      int plane = linear >> 12;                                               \
      int rem = linear & 4095;                                                \
      int row = rem >> 8;                                                     \
      int ck  = rem & 255;                                                    \
      const _Float16* srcp = (plane ? hcm : hch)                              \
                           + (size_t)(rowbase + row) * 2048 + ck * 8;         \
      stg[j] = ld_h8_coh(srcp);                                               \
    } }

// write stg[] -> LDS and sync
#define STAGE_COMMIT() {                                                      \
    _Pragma("unroll")                                                         \
    for (int j = 0; j < 16; ++j) {                                            \
      int linear = tid + 512 * j;                                             \
      int plane = linear >> 12;                                               \
      int rem = linear & 4095;                                                \
      int row = rem >> 8;                                                     \
      int ck  = rem & 255;                                                    \
      *(half8_t*)&hS[plane * HMOFF + row * SH + ck * 8] = stg[j];             \
    }                                                                         \
    __syncthreads(); }

#define SPLIT2(E, J) { float e_ = (E); _Float16 h1_ = (_Float16)e_;           \
  float r_ = e_ - (float)h1_; ah[J] = h1_; am[J] = (_Float16)(r_ * 2048.0f); }

#define PROD3(HA, MA) \
  HA = MFMA16(ah, bh0, HA);                                                   \
  MA = MFMA16(ah, bm0, MA);                                                   \
  MA = MFMA16(am, bh0, MA);

#define X_BODY(KB, HA, MA) {                                                  \
      float4 xu = *(const float4*)(xp + (KB) * 32);                           \
      float4 xw = *(const float4*)(xp + (KB) * 32 + 4);                       \
      half8_t ah, am;                                                         \
      SPLIT2(xu.x, 0) SPLIT2(xu.y, 1) SPLIT2(xu.z, 2) SPLIT2(xu.w, 3)         \
      SPLIT2(xw.x, 4) SPLIT2(xw.y, 5) SPLIT2(xw.z, 6) SPLIT2(xw.w, 7)         \
      half8_t bh0 = *(const half8_t*)&w0a[(KB) * 32 + klo * 8];               \
      half8_t bm0 = *(const half8_t*)&w0b[(KB) * 32 + klo * 8];               \
      PROD3(HA, MA) }

#define H0_BODY(KB, HA, MA) {                                                 \
      half8_t ah = *(const half8_t*)&hS[c16 * SH + (KB) * 32 + klo * 8];      \
      half8_t am = *(const half8_t*)&hS[HMOFF + c16 * SH + (KB) * 32 + klo * 8]; \
      half8_t bh0 = *(const half8_t*)&w0a[512 + (KB) * 32 + klo * 8];         \
      half8_t bm0 = *(const half8_t*)&w0b[512 + (KB) * 32 + klo * 8];         \
      PROD3(HA, MA) }

#define H1_BODY(KB, HA, MA) {                                                 \
      half8_t ah = *(const half8_t*)&hS[c16 * SH + (KB) * 32 + klo * 8];      \
      half8_t am = *(const half8_t*)&hS[HMOFF + c16 * SH + (KB) * 32 + klo * 8]; \
      half8_t bh0 = *(const half8_t*)&w1a[(KB) * 32 + klo * 8];               \
      half8_t bm0 = *(const half8_t*)&w1b[(KB) * 32 + klo * 8];               \
      PROD3(HA, MA) }

#define STAT_ADD(V, BUF) {                                                    \
    _Pragma("unroll")                                                         \
    for (int r = 0; r < 4; ++r) {                                             \
      float s = V[r];                                                         \
      float q = V[r]*V[r];                                                    \
      _Pragma("unroll")                                                       \
      for (int m = 1; m <= 8; m <<= 1) { s += __shfl_xor(s, m); q += __shfl_xor(q, m); } \
      if (c16 == 0) {                                                         \
        int row = rowbase + klo * 4 + r;                                      \
        atomicAdd(&stats[(repbase + (BUF)) * 256 + row * 2 + 0], s);          \
        atomicAdd(&stats[(repbase + (BUF)) * 256 + row * 2 + 1], q);          \
      }                                                                       \
    } }

// LN + LSTM cell. Stats read: lane c16 loads replica c16, shuffle-sum (16 reps).
#define CELL(V, BUF, CS, GC, BEC, HB) {                                       \
    _Pragma("unroll")                                                         \
    for (int r = 0; r < 4; ++r) {                                             \
      int row = rowbase + klo * 4 + r;                                        \
      const float* sp = stats + ((c16 << 2) + (BUF)) * 256 + row * 2;         \
      float s_ = ld_f_coh(sp), q_ = ld_f_coh(sp + 1);                         \
      _Pragma("unroll")                                                       \
      for (int m = 1; m <= 8; m <<= 1) { s_ += __shfl_xor(s_, m); q_ += __shfl_xor(q_, m); } \
      float mean = s_ * (1.0f / 4096.0f);                                     \
      float msq  = q_ * (1.0f / 4096.0f);                                     \
      float rstd = rsqrtf(msq - mean * mean + 1e-5f);                         \
      float gh = (V[r] - mean) * rstd * GC + BEC;                             \
      float fg = __shfl_down(gh, 4);                                          \
      float gg = __shfl_down(gh, 8);                                          \
      float og = __shfl_down(gh, 12);                                         \
      if (c16 < 4) {                                                          \
        float iv = sigm(gh), fv = sigm(fg), zv = tanh_fast(gg), ov = sigm(og); \
        float cc = fv * CS[r] + iv * zv;                                      \
        CS[r] = cc;                                                           \
        float hv = ov * tanh_fast(cc);                                        \
        int idx = row * 2048 + (HB) + cbase + c16;                            \
        _Float16 h1v = (_Float16)hv;                                          \
        st_h_coh(&hch[idx], h1v);                                             \
        st_h_coh(&hcm[idx], (_Float16)((hv - (float)h1v) * 2048.0f));         \
      }                                                                       \
    } }

  f32x4_t ahe, aho, ame, amo;     // layer-0 accumulators
  f32x4_t dhe, dho, dme, dmo;     // layer-1 accumulators
  f32x4_t a0, d0;

  // A0 X-part (h-independent; zeroes the a-chains). kb order = r10/r13 per chain.
#define A0_X(TT) {                                                            \
    ahe = {0,0,0,0}; aho = {0,0,0,0}; ame = {0,0,0,0}; amo = {0,0,0,0};       \
    const float* xp = xbase + (size_t)(TT) * 512 + klo * 8;                   \
    _Pragma("unroll 2")                                                       \
    for (int kb = 0; kb < 16; kb += 2) {                                      \
      X_BODY(kb,     ahe, ame);                                               \
      X_BODY(kb + 1, aho, amo);                                               \
    } }

#define A0_COMBINE() {                                                        \
    a0 = (ahe + aho) * 0.03125f + (ame + amo) * (1.0f / 65536.0f);            \
    _Pragma("unroll")                                                         \
    for (int r_ = 0; r_ < 4; ++r_) a0[r_] += b0v; }

  // ---------------- prologue: A0[0] (h planes are zeroed) ----------------
  STAGE_ISSUE();
  STAGE_COMMIT();
  A0_X(0);
  #pragma unroll 2
  for (int kb = 0; kb < 32; kb += 2) {
    H0_BODY(kb,     ahe, ame);
    H0_BODY(kb + 1, aho, amo);
  }
  A0_COMBINE();
  STAT_ADD(a0, 0);
  groupbar(bars, mtile, tid, ++ep);
  CELL(a0, 0, c0s, g0v, be0v, 0);
  groupbar(bars, mtile, tid, ++ep);

  // ---------------- main loop ----------------
  for (int t = 0; t < 512; ++t) {
    const int par = t & 1;
    const int npar = 1 - par;

    // ===== alpha[t]: async stage under A0_X(t+1); FUSED H1 + A0_H0 =====
    STAGE_ISSUE();                 // coherent loads in flight...
    if (t < 511) {
      A0_X(t + 1);                 // ...hidden under h-independent X-part
    }
    STAGE_COMMIT();                // drain + LDS write + syncthreads

    dhe = {0,0,0,0}; dho = {0,0,0,0}; dme = {0,0,0,0}; dmo = {0,0,0,0};
    if (t < 511) {
      // fused: 2 independent weight streams (w1 + w0) -> deeper MLP;
      // per-chain kb order identical to r13 (bit-identical accumulation)
      #pragma unroll 2
      for (int i = 0; i < 32; i += 2) {
        H1_BODY(2*i,     dhe, dme);
        H1_BODY(2*i+1,   dho, dmo);
        H0_BODY(i,       ahe, ame);
        H1_BODY(2*i+2,   dhe, dme);
        H1_BODY(2*i+3,   dho, dmo);
        H0_BODY(i+1,     aho, amo);
      }
    } else {
      #pragma unroll 2
      for (int kb = 0; kb < 64; kb += 2) {
        H1_BODY(kb,     dhe, dme);
        H1_BODY(kb + 1, dho, dmo);
      }
    }
    d0 = (dhe + dho) * 0.03125f + (dme + dmo) * (1.0f / 65536.0f);
    #pragma unroll
    for (int r = 0; r < 4; ++r) d0[r] += b1v;
    STAT_ADD(d0, 2 + par);

    if (t < 511) {
      A0_COMBINE();
      STAT_ADD(a0, npar);
    }

    // group-local stats zeroing: colgrp<16 zeroes replica=colgrp for this
    // group's 32 entries of the two buffers alpha[t+1] will accumulate
    if (colgrp < 16 && tid < 64) {
      int bufsel = ((tid >> 5) == 0) ? (2 + npar) : par;
      st_f_coh(&stats[((colgrp << 2) + bufsel) * 256 + mtile * 32 + (tid & 31)], 0.0f);
    }

    groupbar(bars, mtile, tid, ++ep);

    // ===== beta[t]: B1[t] (+ B0[t+1]) =====
    CELL(d0, 2 + par, c1s, g1v, be1v, 1024);
    if (t < 511) {
      CELL(a0, npar, c0s, g0v, be0v, 0);
    }
    groupbar(bars, mtile, tid, ++ep);
  }

  // ---------------- final fc (group-local): out rows = this mtile ----------
  // WG (mtile, colgrp) computes rows [16m,16m+16) x cols [16c,16c+16).
  {
    if (tid < 256) {
      int b = rowbase + (tid >> 4);
      int o = colgrp * 16 + (tid & 15);
      const _Float16* p1 = hch + (size_t)b * 2048 + 1024;
      const _Float16* p2 = hcm + (size_t)b * 2048 + 1024;
      float s = fcb[o];
      #pragma unroll 4
      for (int k = 0; k < 1024; k += 4) {
        union { u64 q; _Float16 h[4]; } ua, um;
        ua.q = __hip_atomic_load((u64*)(p1 + k), __ATOMIC_RELAXED, __HIP_MEMORY_SCOPE_SYSTEM);
        um.q = __hip_atomic_load((u64*)(p2 + k), __ATOMIC_RELAXED, __HIP_MEMORY_SCOPE_SYSTEM);
        #pragma unroll
        for (int i = 0; i < 4; ++i) {
          float h = (float)ua.h[i] + (float)um.h[i] * (1.0f / 2048.0f);
          s = fmaf(h, fcW[(k + i) * 512 + o], s);
        }
      }
      out[b * 512 + o] = s;
    }
  }
}

extern "C" void kernel_launch(void* const* d_in, const int* in_sizes, int n_in,
                              void* d_out, int out_size, void* d_ws, size_t ws_size,
                              hipStream_t stream) {
  const float* x   = (const float*)d_in[0];
  const float* W0  = (const float*)d_in[1];
  const float* b0  = (const float*)d_in[2];
  const float* g0  = (const float*)d_in[3];
  const float* be0 = (const float*)d_in[4];
  const float* W1  = (const float*)d_in[5];
  const float* b1  = (const float*)d_in[6];
  const float* g1  = (const float*)d_in[7];
  const float* be1 = (const float*)d_in[8];
  const float* fcW = (const float*)d_in[9];
  const float* fcb = (const float*)d_in[10];
  float* out = (float*)d_out;

  char* ws = (char*)d_ws;
  _Float16* W0a  = (_Float16*)(ws);
  _Float16* W0b  = (_Float16*)(ws + 12582912);
  _Float16* W1a  = (_Float16*)(ws + 25165824);
  _Float16* W1b  = (_Float16*)(ws + 41943040);
  float* vecs    = (float*)(ws + 58720256);
  _Float16* hch  = (_Float16*)(ws + 58818560);
  _Float16* hcm  = (_Float16*)(ws + 59342848);
  float* stats   = (float*)(ws + 59867136);
  unsigned* bars = (unsigned*)(ws + 59932672);

  // re-zero h planes + stats + barrier state every call (graph replays reuse ws)
  hipMemsetAsync(hch, 0, 524288 + 524288 + 65536 + 8192, stream);
  lstm_prep<<<7264, 256, 0, stream>>>(W0, W1, b0, g0, be0, b1, g1, be1,
                                      W0a, W0b, W1a, W1b, vecs);

  hipFuncSetAttribute((const void*)lstm_seq,
                      hipFuncAttributeMaxDynamicSharedMemorySize, LDS_BYTES);
  void* args[] = { (void*)&x, (void*)&W0a, (void*)&W0b, (void*)&W1a, (void*)&W1b,
                   (void*)&vecs, (void*)&hch, (void*)&hcm,
                   (void*)&stats, (void*)&bars,
                   (void*)&fcW, (void*)&fcb, (void*)&out };
  hipError_t lerr = hipLaunchCooperativeKernel((const void*)lstm_seq,
                                               dim3(256), dim3(512),
                                               args, LDS_BYTES, stream);
  if (lerr != hipSuccess) {
    // coop validator rejected (>64KB-LDS occupancy calc). Grid=256 = #CUs at
    // 1 WG/CU -> co-residency capacity-guaranteed; plain launch + own barrier.
    (void)hipGetLastError();
    lstm_seq<<<dim3(256), dim3(512), LDS_BYTES, stream>>>(
        x, W0a, W0b, W1a, W1b, vecs, hch, hcm, stats, bars, fcW, fcb, out);
  }
}